// Round 1
// baseline (662.262 us; speedup 1.0000x reference)
//
#include <hip/hip_runtime.h>

#define NRUNS  128
#define TSTEPS 2048
#define NAG    16
#define SENS   7
#define HID    22

// DPP add: v += dpp(v). CTRL: 0xB1 = quad_perm[1,0,3,2] (xor1),
// 0x4E = quad_perm[2,3,0,1] (xor2), 0x141 = row_half_mirror (xor within 8).
template<int CTRL>
__device__ __forceinline__ float dpp_add(float v) {
    int m = __builtin_amdgcn_update_dpp(0, __float_as_int(v), CTRL, 0xf, 0xf, true);
    return v + __int_as_float(m);
}

__device__ __forceinline__ float bperm(int byteaddr, float v) {
    return __int_as_float(__builtin_amdgcn_ds_bpermute(byteaddr, __float_as_int(v)));
}

__global__ void __launch_bounds__(64, 1) comm_net_kernel(
    const float* __restrict__ runs,       // [128][2048][16][7]
    const float* __restrict__ comm_init,  // [128][18]
    const float* __restrict__ W1,         // [22][9]
    const float* __restrict__ b1,         // [22]
    const float* __restrict__ W2,         // [2][22]
    const float* __restrict__ b2,         // [2]
    float* __restrict__ out)              // [128][2048][16]
{
    const int run  = blockIdx.x;
    const int lane = threadIdx.x & 63;
    const int g    = lane >> 3;   // agent group 0..7, handles agent 2g+parity
    const int sub  = lane & 7;    // sub-lane within group: 3 hidden units each

    // ---- per-lane weight slices (units 3*sub .. 3*sub+2, padded to 24) ----
    float w1x[3][SENS], wA[3], wB[3], b1v[3], w20[3], w21[3];
#pragma unroll
    for (int u = 0; u < 3; ++u) {
        int j = sub * 3 + u;
        bool valid = (j < HID);
        int jj = valid ? j : 0;
        float m = valid ? 1.0f : 0.0f;
#pragma unroll
        for (int k = 0; k < SENS; ++k) w1x[u][k] = m * W1[jj * (SENS + 2) + k];
        wA[u]  = m * W1[jj * (SENS + 2) + 7];   // weight on comm[i]
        wB[u]  = m * W1[jj * (SENS + 2) + 8];   // weight on comm[i+2]
        b1v[u] = m * b1[jj];
        w20[u] = m * W2[jj];          // control row
        w21[u] = m * W2[HID + jj];    // comm row
    }
    const float b20 = b2[0], b21 = b2[1];

    // cross-group shuffle addresses (pull semantics)
    const int addr_even = ((lane - 8) & 63) * 4;  // from group g-1 (even steps)
    const int addr_odd  = ((lane + 8) & 63) * 4;  // from group g+1 (odd steps)
    const bool is_g0 = (g == 0);
    const bool is_g7 = (g == 7);

    const float* ci = comm_init + run * (NAG + 2);
    // prevV = group's virtual "odd-step output" before start = comm_init[2g+2]
    float prevV = ci[2 * g + 2];
    const float initV_e = ci[2 * g + 1];  // emitted at even step while t<0
    const float initV_o = ci[2 * g + 2];  // emitted at odd step while t<0

    const float* pr = runs + (size_t)run * TSTEPS * NAG * SENS;
    float*       po = out  + (size_t)run * TSTEPS * NAG;

    // NN eval for this group's agent; o0=control, o1=new comm (group-reduced)
    auto eval = [&](float cL, float cR, const float* x, float& o0, float& o1) {
        float p0 = 0.f, p1 = 0.f;
#pragma unroll
        for (int u = 0; u < 3; ++u) {
            float a = b1v[u];
#pragma unroll
            for (int k = 0; k < SENS; ++k) a = fmaf(w1x[u][k], x[k], a);
            a = fmaf(wA[u], cL, a);
            a = fmaf(wB[u], cR, a);
            a = fmaxf(a, 0.f);
            p0 = fmaf(w20[u], a, p0);
            p1 = fmaf(w21[u], a, p1);
        }
        // 8-lane butterfly (all lanes end with the group sum)
        p0 = dpp_add<0xB1>(p0);  p1 = dpp_add<0xB1>(p1);
        p0 = dpp_add<0x4E>(p0);  p1 = dpp_add<0x4E>(p1);
        p0 = dpp_add<0x141>(p0); p1 = dpp_add<0x141>(p1);
        o0 = p0 + b20;
        o1 = p1 + b21;
    };

    // guarded pair (even step s, odd step s+1) for pipeline ramp in/out
    auto generic_pair = [&](int s) {
        int t  = (s >> 1) - g;
        int tc = t < 0 ? 0 : (t >= TSTEPS ? TSTEPS - 1 : t);
        const float* x = pr + ((size_t)tc * NAG + 2 * g) * SENS;
        float xa[2 * SENS];
#pragma unroll
        for (int k = 0; k < 2 * SENS; ++k) xa[k] = x[k];
        bool inr = (t >= 0) && (t < TSTEPS);
        {   // even sub-step: agent i = 2g ; cL = comm[i] (cross), cR = own prev
            float cross = bperm(addr_even, prevV);
            float cL = is_g0 ? 0.f : cross;
            float o0, o1;
            eval(cL, prevV, xa, o0, o1);
            if (inr) po[(size_t)t * NAG + 2 * g] = o0;
            prevV = (t < 0) ? initV_e : o1;
        }
        {   // odd sub-step: agent i = 2g+1 ; cL = own prev, cR = cross
            float cross = bperm(addr_odd, prevV);
            float cR = is_g7 ? 0.f : cross;
            float o0, o1;
            eval(prevV, cR, xa + SENS, o0, o1);
            if (inr) po[(size_t)t * NAG + 2 * g + 1] = o0;
            prevV = (t < 0) ? initV_o : o1;
        }
    };

    // ---- ramp-in: s = 0..15 (8 guarded pairs) ----
#pragma unroll 1
    for (int s = 0; s <= 14; s += 2) generic_pair(s);

    // ---- steady state: s = 16 .. 2T-1 ; t = s/2 - g in [0,T) for all ----
    const float* xe = pr + ((size_t)(8 - g) * NAG + 2 * g) * SENS;
    float*       oe = po + ((size_t)(8 - g) * NAG + 2 * g);

    float xA[2 * SENS], xB[2 * SENS];
#pragma unroll
    for (int k = 0; k < 2 * SENS; ++k) xA[k] = xe[k];
    xe += NAG * SENS;

    auto steady_pair = [&](const float* xb) {
        float cross = bperm(addr_even, prevV);
        float cL = is_g0 ? 0.f : cross;
        float o0, o1;
        eval(cL, prevV, xb, o0, o1);
        oe[0] = o0;          // all 8 lanes, same addr & value
        prevV = o1;
        float cross2 = bperm(addr_odd, prevV);
        float cR = is_g7 ? 0.f : cross2;
        eval(prevV, cR, xb + SENS, o0, o1);
        oe[1] = o0;
        prevV = o1;
        oe += NAG;
    };

    const int NSTEADY = TSTEPS - 8;   // 2040 pairs
#pragma unroll 1
    for (int it = 0; it < NSTEADY - 2; it += 2) {
#pragma unroll
        for (int k = 0; k < 2 * SENS; ++k) xB[k] = xe[k];
        xe += NAG * SENS;
        steady_pair(xA);
#pragma unroll
        for (int k = 0; k < 2 * SENS; ++k) xA[k] = xe[k];
        xe += NAG * SENS;
        steady_pair(xB);
    }
    // last two pairs (no further prefetch -> no out-of-bounds reads)
#pragma unroll
    for (int k = 0; k < 2 * SENS; ++k) xB[k] = xe[k];
    steady_pair(xA);
    steady_pair(xB);

    // ---- ramp-out: s = 2T .. 2T+13 (7 guarded pairs) ----
#pragma unroll 1
    for (int s = 2 * TSTEPS; s <= 2 * TSTEPS + 12; s += 2) generic_pair(s);
}

extern "C" void kernel_launch(void* const* d_in, const int* in_sizes, int n_in,
                              void* d_out, int out_size, void* d_ws, size_t ws_size,
                              hipStream_t stream) {
    const float* runs      = (const float*)d_in[0];
    const float* comm_init = (const float*)d_in[1];
    const float* W1        = (const float*)d_in[2];
    const float* b1        = (const float*)d_in[3];
    const float* W2        = (const float*)d_in[4];
    const float* b2        = (const float*)d_in[5];
    float* out = (float*)d_out;

    dim3 grid(NRUNS), block(64);
    hipLaunchKernelGGL(comm_net_kernel, grid, block, 0, stream,
                       runs, comm_init, W1, b1, W2, b2, out);
}

// Round 3
// 456.427 us; speedup vs baseline: 1.4510x; 1.4510x over previous
//
#include <hip/hip_runtime.h>

#define NRUNS  128
#define TSTEPS 2048
#define NAG    16
#define SENS   7
#define HID    22

typedef float float2v __attribute__((ext_vector_type(2)));

// DPP move with bound_ctrl=1. 0xB1 quad_perm[1,0,3,2] (xor1),
// 0x4E quad_perm[2,3,0,1] (xor2), 0x141 row_half_mirror (xor4 within 8).
template<int CTRL>
__device__ __forceinline__ float dpp_mov(float v) {
    return __int_as_float(__builtin_amdgcn_update_dpp(
        0, __float_as_int(v), CTRL, 0xf, 0xf, true));
}

__device__ __forceinline__ float grp_reduce(float v) {
    v += dpp_mov<0xB1>(v);
    v += dpp_mov<0x4E>(v);
    v += dpp_mov<0x141>(v);
    return v;   // all 8 lanes of each aligned 8-lane group hold the group sum
}

__device__ __forceinline__ float bperm(int byteaddr, float v) {
    return __int_as_float(__builtin_amdgcn_ds_bpermute(byteaddr, __float_as_int(v)));
}

struct RawBlk { float2v v[4][7]; };               // 4 pairs x 14 floats
struct XpBlk  { float e[4][3]; float o[4][3]; };  // precomputed x-parts

__global__ void __launch_bounds__(64, 1) comm_net_kernel(
    const float* __restrict__ runs,       // [128][2048][16][7]
    const float* __restrict__ comm_init,  // [128][18]
    const float* __restrict__ W1,         // [22][9]
    const float* __restrict__ b1,         // [22]
    const float* __restrict__ W2,         // [2][22]
    const float* __restrict__ b2,         // [2]
    float* __restrict__ out)              // [128][2048][16]
{
    const int run  = blockIdx.x;
    const int lane = threadIdx.x & 63;
    const int g    = lane >> 3;   // agent group 0..7 (agents 2g, 2g+1)
    const int sub  = lane & 7;    // 3 hidden units per sub-lane (22 padded to 24)
    const bool g0  = (g == 0);
    const bool g7  = (g == 7);

    // ---- per-lane weight slices ----
    float w1x[3][SENS], wA[3], wB[3], b1v[3], w20[3], w21[3];
#pragma unroll
    for (int u = 0; u < 3; ++u) {
        int j = sub * 3 + u;
        bool valid = (j < HID);
        int jj = valid ? j : 0;
        float m = valid ? 1.0f : 0.0f;
#pragma unroll
        for (int k = 0; k < SENS; ++k) w1x[u][k] = m * W1[jj * 9 + k];
        wA[u]  = m * W1[jj * 9 + 7];   // weight on comm[i]
        wB[u]  = m * W1[jj * 9 + 8];   // weight on comm[i+2]
        b1v[u] = m * b1[jj];
        w20[u] = m * W2[jj];           // control row
        w21[u] = m * W2[HID + jj];     // comm row
    }
    const float b20 = b2[0], b21 = b2[1];

    const int addr_even = ((lane - 8) & 63) * 4;  // pull from group g-1
    const int addr_odd  = ((lane + 8) & 63) * 4;  // pull from group g+1

    const float* ci = comm_init + run * (NAG + 2);
    float prevV = ci[2 * g + 2];
    const float initV_e = ci[2 * g + 1];
    const float initV_o = ci[2 * g + 2];

    const float* pr = runs + (size_t)run * TSTEPS * NAG * SENS;
    float*       po = out  + (size_t)run * TSTEPS * NAG;

    // x-part for one pair: ae/ao = b1 + W1x . x  (even/odd agent)
    auto xpart_pair = [&](const float2v (&r)[7], float (&ae)[3], float (&ao)[3]) {
#pragma unroll
        for (int u = 0; u < 3; ++u) {
            float e = b1v[u];
            e = fmaf(w1x[u][0], r[0].x, e);
            e = fmaf(w1x[u][1], r[0].y, e);
            e = fmaf(w1x[u][2], r[1].x, e);
            e = fmaf(w1x[u][3], r[1].y, e);
            e = fmaf(w1x[u][4], r[2].x, e);
            e = fmaf(w1x[u][5], r[2].y, e);
            e = fmaf(w1x[u][6], r[3].x, e);
            ae[u] = e;
            float o = b1v[u];
            o = fmaf(w1x[u][0], r[3].y, o);
            o = fmaf(w1x[u][1], r[4].x, o);
            o = fmaf(w1x[u][2], r[4].y, o);
            o = fmaf(w1x[u][3], r[5].x, o);
            o = fmaf(w1x[u][4], r[5].y, o);
            o = fmaf(w1x[u][5], r[6].x, o);
            o = fmaf(w1x[u][6], r[6].y, o);
            ao[u] = o;
        }
    };

    // even sub-step: agent 2g. cL = comm[2g] from group g-1, cR = own prevV.
    auto substep_even = [&](float xe0, float xe1, float xe2, float& o0out) {
        float cross = bperm(addr_even, prevV);
        float cL = g0 ? 0.f : cross;
        float a0 = fmaxf(fmaf(wA[0], cL, fmaf(wB[0], prevV, xe0)), 0.f);
        float a1 = fmaxf(fmaf(wA[1], cL, fmaf(wB[1], prevV, xe1)), 0.f);
        float a2 = fmaxf(fmaf(wA[2], cL, fmaf(wB[2], prevV, xe2)), 0.f);
        float p0 = w20[0] * a0; p0 = fmaf(w20[1], a1, p0); p0 = fmaf(w20[2], a2, p0);
        float p1 = w21[0] * a0; p1 = fmaf(w21[1], a1, p1); p1 = fmaf(w21[2], a2, p1);
        o0out = grp_reduce(p0) + b20;
        prevV = grp_reduce(p1) + b21;        // comm[2g+1]
    };
    // odd sub-step: agent 2g+1. cL = own prevV, cR = comm[2g+3] from group g+1.
    auto substep_odd = [&](float xo0, float xo1, float xo2, float& o0out) {
        float cross = bperm(addr_odd, prevV);
        float cR = g7 ? 0.f : cross;
        float a0 = fmaxf(fmaf(wB[0], cR, fmaf(wA[0], prevV, xo0)), 0.f);
        float a1 = fmaxf(fmaf(wB[1], cR, fmaf(wA[1], prevV, xo1)), 0.f);
        float a2 = fmaxf(fmaf(wB[2], cR, fmaf(wA[2], prevV, xo2)), 0.f);
        float p0 = w20[0] * a0; p0 = fmaf(w20[1], a1, p0); p0 = fmaf(w20[2], a2, p0);
        float p1 = w21[0] * a0; p1 = fmaf(w21[1], a1, p1); p1 = fmaf(w21[2], a2, p1);
        o0out = grp_reduce(p0) + b20;
        prevV = grp_reduce(p1) + b21;        // comm[2g+2]
    };

    // guarded pair for pipeline ramp in/out (15 total — slow path OK)
    auto ramp_pair = [&](int s) {
        int t  = (s >> 1) - g;
        int tc = t < 0 ? 0 : (t > TSTEPS - 1 ? TSTEPS - 1 : t);
        const float2v* xp = (const float2v*)(pr + ((size_t)tc * NAG + 2 * g) * SENS);
        float2v r[7];
#pragma unroll
        for (int k = 0; k < 7; ++k) r[k] = xp[k];
        float ae[3], ao[3];
        xpart_pair(r, ae, ao);
        bool inr = (t >= 0) && (t < TSTEPS);
        float o0;
        substep_even(ae[0], ae[1], ae[2], o0);
        if (inr) po[(size_t)t * NAG + 2 * g] = o0;
        prevV = (t < 0) ? initV_e : prevV;
        substep_odd(ao[0], ao[1], ao[2], o0);
        if (inr) po[(size_t)t * NAG + 2 * g + 1] = o0;
        prevV = (t < 0) ? initV_o : prevV;
    };

    // ---- ramp-in: global steps s=0..15 (8 pairs) ----
#pragma unroll 1
    for (int s = 0; s <= 14; s += 2) ramp_pair(s);

    // ---- steady: 2040 pairs (510 blocks of 4), t = pair + 8 - g, all in range ----
    const float2v* xv = (const float2v*)(pr + ((size_t)(8 - g) * NAG + 2 * g) * SENS);
    float* oe = po + (size_t)(8 - g) * NAG + 2 * g;

    RawBlk RA, RB;
    XpBlk  P0, P1;

    auto load_blk = [&](RawBlk& R, const float2v* p) {
#pragma unroll
        for (int j = 0; j < 4; ++j)
#pragma unroll
            for (int k = 0; k < 7; ++k)
                R.v[j][k] = p[j * 56 + k];
    };
    auto xpart_blk = [&](XpBlk& P, const RawBlk& R) {
#pragma unroll
        for (int j = 0; j < 4; ++j) xpart_pair(R.v[j], P.e[j], P.o[j]);
    };
    auto process_blk = [&](const XpBlk& P) {
#pragma unroll
        for (int j = 0; j < 4; ++j) {
            float o0;
            substep_even(P.e[j][0], P.e[j][1], P.e[j][2], o0);
            oe[0] = o0;
            substep_odd(P.o[j][0], P.o[j][1], P.o[j][2], o0);
            oe[1] = o0;
            oe += NAG;
        }
    };

    // pipeline fill: P0 = xparts(block0), RB = raws(block1), RA = raws(block2)
    load_blk(RA, xv);
    load_blk(RB, xv + 224);
    xpart_blk(P0, RA);
    load_blk(RA, xv + 2 * 224);

#pragma unroll 1
    for (int bm = 0; bm < 506; bm += 2) {
        xpart_blk(P1, RB);                             // block bm+1
        load_blk(RB, xv + (size_t)(bm + 3) * 224);
        process_blk(P0);                               // block bm
        xpart_blk(P0, RA);                             // block bm+2
        load_blk(RA, xv + (size_t)(bm + 4) * 224);
        process_blk(P1);                               // block bm+1
    }
    // epilogue: blocks 506..509 (loads stay in-bounds)
    xpart_blk(P1, RB);                                 // 507
    load_blk(RB, xv + (size_t)509 * 224);
    process_blk(P0);                                   // 506
    xpart_blk(P0, RA);                                 // 508
    process_blk(P1);                                   // 507
    xpart_blk(P1, RB);                                 // 509
    process_blk(P0);                                   // 508
    process_blk(P1);                                   // 509

    // ---- ramp-out: 7 guarded pairs ----
#pragma unroll 1
    for (int s = 2 * TSTEPS; s <= 2 * TSTEPS + 12; s += 2) ramp_pair(s);
}

extern "C" void kernel_launch(void* const* d_in, const int* in_sizes, int n_in,
                              void* d_out, int out_size, void* d_ws, size_t ws_size,
                              hipStream_t stream) {
    const float* runs      = (const float*)d_in[0];
    const float* comm_init = (const float*)d_in[1];
    const float* W1        = (const float*)d_in[2];
    const float* b1        = (const float*)d_in[3];
    const float* W2        = (const float*)d_in[4];
    const float* b2        = (const float*)d_in[5];
    float* out = (float*)d_out;

    dim3 grid(NRUNS), block(64);
    hipLaunchKernelGGL(comm_net_kernel, grid, block, 0, stream,
                       runs, comm_init, W1, b1, W2, b2, out);
}